// Round 4
// baseline (547.996 us; speedup 1.0000x reference)
//
#include <hip/hip_runtime.h>
#include <hip/hip_bf16.h>
#include <stdint.h>

// MoE gate: logits = r @ W^T + b ; soft = softmax(logits) ; hard = top8-renorm
// r: (32768, 2048) fp32, W: (64, 2048) fp32, b: (64,) fp32
// d_out: [hard (32768*64) | soft (32768*64)] fp32
//
// Precision: exact bf16^3 split of both operands, 6 MFMA terms in 3 scale-
// class accumulators (rounds 2-3 verified: absmax 0.00195 vs 0.01625 thr).
//
// Perf history: r2 277us (VGPR=56 serialized loads), r3 175us (LDS dbuf, but
// per-k-step __syncthreads -> s_waitcnt vmcnt(0) drain = 6.5K cyc/step vs
// ~630 cyc of work). r4: BARRIER-FREE K-loop. B read straight from global
// (fragment-ordered 16B/lane, L1/L2-resident 768 KB shared by all waves) into
// an explicit register double-buffer; A prefetched at distance 2. ~14 VMEM
// in flight per wave continuously, no drains.

#define D_DIM 2048
#define E_DIM 64
#define B_DIM 32768
#define TOPK 8

typedef __bf16 bf16x8 __attribute__((ext_vector_type(8)));
typedef float f32x4 __attribute__((ext_vector_type(4)));

// ---- prep: W fp32 -> 3 bf16 splits in workspace (3 * 131072 elems = 768 KB) ----
__global__ __launch_bounds__(256) void w_split3(const float* __restrict__ W,
                                                __bf16* __restrict__ W1,
                                                __bf16* __restrict__ W2,
                                                __bf16* __restrict__ W3) {
    int i = (blockIdx.x * 256 + threadIdx.x) * 8;  // 64 blocks
    bf16x8 o1, o2, o3;
    #pragma unroll
    for (int j = 0; j < 8; ++j) {
        float x  = W[i + j];
        __bf16 h1 = (__bf16)x;
        float r1 = x - (float)h1;          // exact
        __bf16 h2 = (__bf16)r1;
        float r2 = r1 - (float)h2;         // exact
        o1[j] = h1; o2[j] = h2; o3[j] = (__bf16)r2;
    }
    *(bf16x8*)(W1 + i) = o1;
    *(bf16x8*)(W2 + i) = o2;
    *(bf16x8*)(W3 + i) = o3;
}

// ---- main: 6-term split GEMM + fused softmax/top-8, barrier-free K-loop ----
// Block = 256 thr = 4 waves; wave owns 16 rows x 64 experts. Grid = 512.
__global__ __launch_bounds__(256) void moe_gate(const float* __restrict__ r,
                                                const __bf16* __restrict__ W1,
                                                const __bf16* __restrict__ W2,
                                                const __bf16* __restrict__ W3,
                                                const float* __restrict__ bias,
                                                float* __restrict__ out) {
    __shared__ float lg[64][E_DIM + 1];   // logits tile (epilogue only)

    const int t    = threadIdx.x;
    const int wv   = t >> 6;
    const int lane = t & 63;
    const int lrow = lane & 15;
    const int quad = lane >> 4;
    const int row0 = blockIdx.x * 64;

    // A: lane holds A[m=lrow][k=quad*8+j]; 16B/lane, 128B per row segment
    const float* ra = r + (size_t)(row0 + wv * 16 + lrow) * D_DIM + quad * 8;
    // B: lane holds B[k=quad*8+j][n=lrow] == Wsplit[n-tile*16+lrow][quad*8+j]
    const size_t wofs = (size_t)lrow * D_DIM + quad * 8;
    const __bf16* wp0 = W1 + wofs;
    const __bf16* wp1 = W2 + wofs;
    const __bf16* wp2 = W3 + wofs;

    f32x4 accM[4] = {};  // h1*g1              (~1)
    f32x4 accD[4] = {};  // h1*g2 + h2*g1      (~2^-8)
    f32x4 accL[4] = {};  // h1*g3+h2*g2+h3*g1  (~2^-16)

    bf16x8 Bb[2][3][4];   // register double-buffer for B fragments (96 VGPR)
    float4 Aa[2][2];      // A ping-pong, prefetch distance 2 (16 VGPR)

    // prologue: B(k=0) -> buf0; A(k=0) -> Aa[0]; A(k=32) -> Aa[1]
    #pragma unroll
    for (int n = 0; n < 4; ++n) {
        Bb[0][0][n] = *(const bf16x8*)(wp0 + (size_t)n * 16 * D_DIM);
        Bb[0][1][n] = *(const bf16x8*)(wp1 + (size_t)n * 16 * D_DIM);
        Bb[0][2][n] = *(const bf16x8*)(wp2 + (size_t)n * 16 * D_DIM);
    }
    Aa[0][0] = *(const float4*)(ra);
    Aa[0][1] = *(const float4*)(ra + 4);
    Aa[1][0] = *(const float4*)(ra + 32);
    Aa[1][1] = *(const float4*)(ra + 36);

    auto body = [&](int ks, const int p) __attribute__((always_inline)) {
        const int kB = (ks + 1) * 32;   // next B k-offset -> buffer p^1
        const int kA = (ks + 2) * 32;   // A prefetch distance 2 -> Aa[p]
        if (kB < D_DIM) {
            #pragma unroll
            for (int n = 0; n < 4; ++n) {
                Bb[p ^ 1][0][n] = *(const bf16x8*)(wp0 + (size_t)n * 16 * D_DIM + kB);
                Bb[p ^ 1][1][n] = *(const bf16x8*)(wp1 + (size_t)n * 16 * D_DIM + kB);
                Bb[p ^ 1][2][n] = *(const bf16x8*)(wp2 + (size_t)n * 16 * D_DIM + kB);
            }
        }
        // split current A (loaded 2 iterations ago)
        float av[8] = {Aa[p][0].x, Aa[p][0].y, Aa[p][0].z, Aa[p][0].w,
                       Aa[p][1].x, Aa[p][1].y, Aa[p][1].z, Aa[p][1].w};
        if (kA < D_DIM) {
            Aa[p][0] = *(const float4*)(ra + kA);
            Aa[p][1] = *(const float4*)(ra + kA + 4);
        }
        bf16x8 A1, A2, A3;
        #pragma unroll
        for (int j = 0; j < 8; ++j) {
            float x  = av[j];
            __bf16 h1 = (__bf16)x;
            float r1 = x - (float)h1;
            __bf16 h2 = (__bf16)r1;
            float r2 = r1 - (float)h2;
            A1[j] = h1; A2[j] = h2; A3[j] = (__bf16)r2;
        }
        #pragma unroll
        for (int n = 0; n < 4; ++n) {
            accM[n] = __builtin_amdgcn_mfma_f32_16x16x32_bf16(A1, Bb[p][0][n], accM[n], 0, 0, 0);
            accD[n] = __builtin_amdgcn_mfma_f32_16x16x32_bf16(A1, Bb[p][1][n], accD[n], 0, 0, 0);
            accD[n] = __builtin_amdgcn_mfma_f32_16x16x32_bf16(A2, Bb[p][0][n], accD[n], 0, 0, 0);
            accL[n] = __builtin_amdgcn_mfma_f32_16x16x32_bf16(A1, Bb[p][2][n], accL[n], 0, 0, 0);
            accL[n] = __builtin_amdgcn_mfma_f32_16x16x32_bf16(A2, Bb[p][1][n], accL[n], 0, 0, 0);
            accL[n] = __builtin_amdgcn_mfma_f32_16x16x32_bf16(A3, Bb[p][0][n], accL[n], 0, 0, 0);
        }
    };

    for (int ks = 0; ks < D_DIM / 32; ks += 2) {  // parity is compile-time
        body(ks, 0);
        body(ks + 1, 1);
    }

    // C/D layout: col = lane&15, row = quad*4 + reg. Combine small-first.
    #pragma unroll
    for (int n = 0; n < 4; ++n) {
        int col = n * 16 + lrow;
        float bb = bias[col];
        #pragma unroll
        for (int i = 0; i < 4; ++i) {
            lg[wv * 16 + quad * 4 + i][col] = (accM[n][i] + (accD[n][i] + accL[n][i])) + bb;
        }
    }
    __syncthreads();

    // softmax + top-8; wave per row, lane = expert. TEMPERATURE == 1.0.
    for (int rr = wv; rr < 64; rr += 4) {
        float logit = lg[rr][lane];
        float mx = logit;
        #pragma unroll
        for (int s = 32; s >= 1; s >>= 1) mx = fmaxf(mx, __shfl_xor(mx, s));
        float ex = expf(logit - mx);
        float sm = ex;
        #pragma unroll
        for (int s = 32; s >= 1; s >>= 1) sm += __shfl_xor(sm, s);
        float soft = ex / sm;

        // top-8 on soft (monotone in logit); lowest-index tie-break = lax.top_k
        bool  sel    = false;
        float topsum = 0.0f;
        #pragma unroll
        for (int it = 0; it < TOPK; ++it) {
            float cand = sel ? -1.0f : soft;  // soft > 0 always
            float cm = cand;
            #pragma unroll
            for (int s = 32; s >= 1; s >>= 1) cm = fmaxf(cm, __shfl_xor(cm, s));
            unsigned long long ball = __ballot(cand == cm);
            int leader = __ffsll(ball) - 1;
            if (lane == leader) sel = true;
            topsum += cm;
        }
        float hard = sel ? soft / (topsum + 1e-9f) : 0.0f;

        size_t orow = (size_t)(row0 + rr) * E_DIM + lane;
        out[orow] = hard;
        out[(size_t)B_DIM * E_DIM + orow] = soft;
    }
}

extern "C" void kernel_launch(void* const* d_in, const int* in_sizes, int n_in,
                              void* d_out, int out_size, void* d_ws, size_t ws_size,
                              hipStream_t stream) {
    const float* r = (const float*)d_in[0];
    const float* W = (const float*)d_in[1];
    const float* b = (const float*)d_in[2];
    float* out = (float*)d_out;
    __bf16* W1 = (__bf16*)d_ws;                     // 3 * 262144 B = 768 KB of ws
    __bf16* W2 = W1 + (size_t)E_DIM * D_DIM;
    __bf16* W3 = W2 + (size_t)E_DIM * D_DIM;

    w_split3<<<64, 256, 0, stream>>>(W, W1, W2, W3);
    moe_gate<<<512, 256, 0, stream>>>(r, W1, W2, W3, b, out);
}

// Round 5
// 496.890 us; speedup vs baseline: 1.1029x; 1.1029x over previous
//
#include <hip/hip_runtime.h>
#include <hip/hip_bf16.h>
#include <stdint.h>

// MoE gate: logits = r @ W^T + b ; soft = softmax(logits) ; hard = top8-renorm
// r: (32768, 2048) fp32, W: (64, 2048) fp32, b: (64,) fp32
// d_out: [hard (32768*64) | soft (32768*64)] fp32
//
// Numerics (FROZEN since r2, passes at absmax 0.00195 / thr 0.01625): exact
// bf16^3 split of both operands; per element, per k-step (ascending, step 32):
// accM+=A1B1; accD+=A1B2; accD+=A2B1; accL+=A1B3; accL+=A2B2; accL+=A3B1;
// combine (M + (D + L)) + bias. Any reorder re-rolls top-8 tie-breaks.
//
// r5 structure: EXPERT-SPLIT for TLP. Wave = 16 rows x 16 experts -> 8192
// waves (4x r2-r4 supply). Block = 4 waves = 16 rows x 64 experts, grid 2048.
// A is staged to LDS PRE-SPLIT (split VALU runs once per block, not per
// wave-step); B fragments read direct from global (disjoint per wave; LDS
// staging would save nothing). Barriers: 2 per 128-k chunk (4 MFMA steps);
// only the A-prefetch crosses a drain, with a full compute phase of slack.

#define D_DIM 2048
#define E_DIM 64
#define B_DIM 32768
#define TOPK 8
#define CK    128              // k elements staged per chunk
#define NCH   (D_DIM / CK)     // 16 chunks
#define STEPS (CK / 32)        // 4 MFMA k-steps per chunk
#define AP    134              // As row stride (bf16): 128 + pad 6 (~2-way banks)

typedef __bf16 bf16x8 __attribute__((ext_vector_type(8)));
typedef float f32x4 __attribute__((ext_vector_type(4)));

// ---- prep: W fp32 -> 3 bf16 splits in workspace (3 * 131072 elems = 768 KB) ----
__global__ __launch_bounds__(256) void w_split3(const float* __restrict__ W,
                                                __bf16* __restrict__ W1,
                                                __bf16* __restrict__ W2,
                                                __bf16* __restrict__ W3) {
    int i = (blockIdx.x * 256 + threadIdx.x) * 8;  // 64 blocks
    bf16x8 o1, o2, o3;
    #pragma unroll
    for (int j = 0; j < 8; ++j) {
        float x  = W[i + j];
        __bf16 h1 = (__bf16)x;
        float r1 = x - (float)h1;          // exact
        __bf16 h2 = (__bf16)r1;
        float r2 = r1 - (float)h2;         // exact
        o1[j] = h1; o2[j] = h2; o3[j] = (__bf16)r2;
    }
    *(bf16x8*)(W1 + i) = o1;
    *(bf16x8*)(W2 + i) = o2;
    *(bf16x8*)(W3 + i) = o3;
}

__global__ __launch_bounds__(256, 4) void moe_gate(const float* __restrict__ r,
                                                   const __bf16* __restrict__ W1,
                                                   const __bf16* __restrict__ W2,
                                                   const __bf16* __restrict__ W3,
                                                   const float* __restrict__ bias,
                                                   float* __restrict__ out) {
    __shared__ __bf16 As[3][16][AP];   // pre-split A chunk, 12.9 KB
    __shared__ float  lg[16][E_DIM + 1];

    const int t    = threadIdx.x;
    const int wv   = t >> 6;          // wave = expert tile 0..3
    const int lane = t & 63;
    const int lrow = lane & 15;
    const int quad = lane >> 4;
    const int row0 = blockIdx.x * 16;

    // A staging: thread t owns row ar, cols ac..ac+8 of the 16x128 chunk
    const int ar = t >> 4;
    const int ac = (t & 15) * 8;
    const float* ga = r + (size_t)(row0 + ar) * D_DIM + ac;

    // B fragments: lane holds Wsplit[wv*16 + lrow][ks*32 + quad*8 .. +8]
    const size_t wofs = (size_t)(wv * 16 + lrow) * D_DIM + quad * 8;
    const __bf16* wb1 = W1 + wofs;
    const __bf16* wb2 = W2 + wofs;
    const __bf16* wb3 = W3 + wofs;

    f32x4 accM = {}, accD = {}, accL = {};

    // prologue: A chunk 0 -> regs
    float4 av0 = *(const float4*)(ga);
    float4 av1 = *(const float4*)(ga + 4);
    ga += CK;

    for (int c = 0; c < NCH; ++c) {
        __syncthreads();  // previous chunk's readers done with As

        // split current A chunk (values identical to r2's per-element split)
        {
            float a[8] = {av0.x, av0.y, av0.z, av0.w, av1.x, av1.y, av1.z, av1.w};
            bf16x8 s1, s2, s3;
            #pragma unroll
            for (int j = 0; j < 8; ++j) {
                float x  = a[j];
                __bf16 h1 = (__bf16)x;
                float r1 = x - (float)h1;
                __bf16 h2 = (__bf16)r1;
                float r2 = r1 - (float)h2;
                s1[j] = h1; s2[j] = h2; s3[j] = (__bf16)r2;
            }
            *(bf16x8*)&As[0][ar][ac] = s1;
            *(bf16x8*)&As[1][ar][ac] = s2;
            *(bf16x8*)&As[2][ar][ac] = s3;
        }
        __syncthreads();  // As visible (ds_writes are fast; nothing else in flight)

        // prefetch next A chunk (full compute phase of slack before its drain)
        if (c + 1 < NCH) {
            av0 = *(const float4*)(ga);
            av1 = *(const float4*)(ga + 4);
            ga += CK;
        }

        // burst-issue all 12 B fragment loads for this chunk (static imm offsets)
        bf16x8 B1[STEPS], B2[STEPS], B3[STEPS];
        #pragma unroll
        for (int j = 0; j < STEPS; ++j) {
            B1[j] = *(const bf16x8*)(wb1 + j * 32);
            B2[j] = *(const bf16x8*)(wb2 + j * 32);
            B3[j] = *(const bf16x8*)(wb3 + j * 32);
        }
        wb1 += CK; wb2 += CK; wb3 += CK;

        // 4 MFMA k-steps; A-frag ds_reads are immediate-addressed
        #pragma unroll
        for (int j = 0; j < STEPS; ++j) {
            bf16x8 A1 = *(const bf16x8*)&As[0][lrow][j * 32 + quad * 8];
            bf16x8 A2 = *(const bf16x8*)&As[1][lrow][j * 32 + quad * 8];
            bf16x8 A3 = *(const bf16x8*)&As[2][lrow][j * 32 + quad * 8];
            accM = __builtin_amdgcn_mfma_f32_16x16x32_bf16(A1, B1[j], accM, 0, 0, 0);
            accD = __builtin_amdgcn_mfma_f32_16x16x32_bf16(A1, B2[j], accD, 0, 0, 0);
            accD = __builtin_amdgcn_mfma_f32_16x16x32_bf16(A2, B1[j], accD, 0, 0, 0);
            accL = __builtin_amdgcn_mfma_f32_16x16x32_bf16(A1, B3[j], accL, 0, 0, 0);
            accL = __builtin_amdgcn_mfma_f32_16x16x32_bf16(A2, B2[j], accL, 0, 0, 0);
            accL = __builtin_amdgcn_mfma_f32_16x16x32_bf16(A3, B1[j], accL, 0, 0, 0);
        }
    }

    // C/D layout: col = lane&15 (expert within tile), row = quad*4 + reg.
    {
        const int col = wv * 16 + lrow;
        const float bb = bias[col];
        #pragma unroll
        for (int i = 0; i < 4; ++i)
            lg[quad * 4 + i][col] = (accM[i] + (accD[i] + accL[i])) + bb;
    }
    __syncthreads();

    // softmax + top-8; wave per row, lane = expert. TEMPERATURE == 1.0.
    for (int rr = wv; rr < 16; rr += 4) {
        float logit = lg[rr][lane];
        float mx = logit;
        #pragma unroll
        for (int s = 32; s >= 1; s >>= 1) mx = fmaxf(mx, __shfl_xor(mx, s));
        float ex = expf(logit - mx);
        float sm = ex;
        #pragma unroll
        for (int s = 32; s >= 1; s >>= 1) sm += __shfl_xor(sm, s);
        float soft = ex / sm;

        // top-8 (monotone in logit); lowest-index tie-break = lax.top_k
        bool  sel    = false;
        float topsum = 0.0f;
        #pragma unroll
        for (int it = 0; it < TOPK; ++it) {
            float cand = sel ? -1.0f : soft;  // soft > 0 always
            float cm = cand;
            #pragma unroll
            for (int s = 32; s >= 1; s >>= 1) cm = fmaxf(cm, __shfl_xor(cm, s));
            unsigned long long ball = __ballot(cand == cm);
            int leader = __ffsll(ball) - 1;
            if (lane == leader) sel = true;
            topsum += cm;
        }
        float hard = sel ? soft / (topsum + 1e-9f) : 0.0f;

        size_t orow = (size_t)(row0 + rr) * E_DIM + lane;
        out[orow] = hard;
        out[(size_t)B_DIM * E_DIM + orow] = soft;
    }
}

extern "C" void kernel_launch(void* const* d_in, const int* in_sizes, int n_in,
                              void* d_out, int out_size, void* d_ws, size_t ws_size,
                              hipStream_t stream) {
    const float* r = (const float*)d_in[0];
    const float* W = (const float*)d_in[1];
    const float* b = (const float*)d_in[2];
    float* out = (float*)d_out;
    __bf16* W1 = (__bf16*)d_ws;                     // 3 * 262144 B = 768 KB of ws
    __bf16* W2 = W1 + (size_t)E_DIM * D_DIM;
    __bf16* W3 = W2 + (size_t)E_DIM * D_DIM;

    w_split3<<<64, 256, 0, stream>>>(W, W1, W2, W3);
    moe_gate<<<2048, 256, 0, stream>>>(r, W1, W2, W3, b, out);
}